// Round 2
// baseline (622.797 us; speedup 1.0000x reference)
//
#include <hip/hip_runtime.h>

static constexpr float kEps = 1e-5f;

// ---------------------------------------------------------------------------
// Repack weights: wT[(cin*27+k)*COUT + cout] = w[(cout*CIN+cin)*27 + k] * inv[cout]
// bias[cout] = b[cout] - m[cout]*inv[cout]
// ---------------------------------------------------------------------------
template <int CIN, int COUT>
__global__ __launch_bounds__(256) void repack_kernel(
    const float* __restrict__ w, const float* __restrict__ g,
    const float* __restrict__ b, const float* __restrict__ m,
    const float* __restrict__ v, float* __restrict__ wT,
    float* __restrict__ bias) {
  int idx = blockIdx.x * 256 + threadIdx.x;
  constexpr int total = COUT * CIN * 27;
  if (idx < COUT) {
    float inv = g[idx] * rsqrtf(v[idx] + kEps);
    bias[idx] = b[idx] - m[idx] * inv;
  }
  if (idx < total) {
    int cout = idx % COUT;   // COUT is a power of 2
    int ck = idx / COUT;
    int cin = ck / 27;
    int k = ck % 27;
    float inv = g[cout] * rsqrtf(v[cout] + kEps);
    wT[idx] = w[(cout * CIN + cin) * 27 + k] * inv;
  }
}

// ---------------------------------------------------------------------------
// Direct 3x3x3 stride-2 pad-1 conv + BN(+fold) + ReLU.
// One thread = one output position, CB output channels.
// Weight loads are block-uniform -> scalar loads.
// Even input dims + stride2/pad1 => only lower border can be OOB.
// ---------------------------------------------------------------------------
template <int CIN, int COUT, int CB, int DO, int BLK>
__global__ __launch_bounds__(BLK) void conv_s2_bnrelu(
    const float* __restrict__ in, const float* __restrict__ wT,
    const float* __restrict__ bias, float* __restrict__ out) {
  constexpr int DI = DO * 2;
  int tid = blockIdx.x * BLK + threadIdx.x;
  int coutBase = blockIdx.y * CB;
  int x = tid & (DO - 1);
  int t = tid / DO;
  int y = t & (DO - 1);
  t /= DO;
  int z = t & (DO - 1);
  int bb = t / DO;

  float acc[CB];
#pragma unroll
  for (int i = 0; i < CB; ++i) acc[i] = 0.f;

  const float* inb = in + (size_t)bb * CIN * DI * DI * DI;
  for (int cin = 0; cin < CIN; ++cin) {
    const float* inc = inb + (size_t)cin * DI * DI * DI;
#pragma unroll
    for (int kz = 0; kz < 3; ++kz) {
      int iz = 2 * z + kz - 1;
      if (iz < 0) continue;
#pragma unroll
      for (int ky = 0; ky < 3; ++ky) {
        int iy = 2 * y + ky - 1;
        if (iy < 0) continue;
        const float* row = inc + ((size_t)iz * DI + iy) * DI;
#pragma unroll
        for (int kx = 0; kx < 3; ++kx) {
          int ix = 2 * x + kx - 1;
          float xv = (ix >= 0) ? row[ix] : 0.f;
          const float* wp =
              wT + ((size_t)cin * 27 + (kz * 3 + ky) * 3 + kx) * COUT + coutBase;
#pragma unroll
          for (int i = 0; i < CB; ++i) acc[i] = fmaf(xv, wp[i], acc[i]);
        }
      }
    }
  }
  constexpr int OS = DO * DO * DO;
  float* op = out + ((size_t)bb * COUT + coutBase) * OS + (z * DO + y) * DO + x;
#pragma unroll
  for (int i = 0; i < CB; ++i) {
    float r = fmaxf(acc[i] + bias[coutBase + i], 0.f);
    op[(size_t)i * OS] = r;
  }
}

// ---------------------------------------------------------------------------
// Split-K variant for small-spatial stages (4,5). Writes partials (no bias).
// partial layout: [sk][COUT][NPOS]  (coalesced writes & reads)
// ---------------------------------------------------------------------------
template <int CIN, int COUT, int CB, int DO, int SK, int BLK>
__global__ __launch_bounds__(BLK) void conv_s2_splitk(
    const float* __restrict__ in, const float* __restrict__ wT,
    float* __restrict__ partial) {
  constexpr int DI = DO * 2;
  constexpr int CK = CIN / SK;
  constexpr int NPOS = 2 * DO * DO * DO;
  int tid = blockIdx.x * BLK + threadIdx.x;  // position (incl. batch)
  int coutBase = blockIdx.y * CB;
  int sk = blockIdx.z;
  int x = tid & (DO - 1);
  int t = tid / DO;
  int y = t & (DO - 1);
  t /= DO;
  int z = t & (DO - 1);
  int bb = t / DO;

  float acc[CB];
#pragma unroll
  for (int i = 0; i < CB; ++i) acc[i] = 0.f;

  const float* inb = in + (size_t)bb * CIN * DI * DI * DI;
  for (int cc = 0; cc < CK; ++cc) {
    int cin = sk * CK + cc;
    const float* inc = inb + (size_t)cin * DI * DI * DI;
#pragma unroll
    for (int kz = 0; kz < 3; ++kz) {
      int iz = 2 * z + kz - 1;
      if (iz < 0) continue;
#pragma unroll
      for (int ky = 0; ky < 3; ++ky) {
        int iy = 2 * y + ky - 1;
        if (iy < 0) continue;
        const float* row = inc + ((size_t)iz * DI + iy) * DI;
#pragma unroll
        for (int kx = 0; kx < 3; ++kx) {
          int ix = 2 * x + kx - 1;
          float xv = (ix >= 0) ? row[ix] : 0.f;
          const float* wp =
              wT + ((size_t)cin * 27 + (kz * 3 + ky) * 3 + kx) * COUT + coutBase;
#pragma unroll
          for (int i = 0; i < CB; ++i) acc[i] = fmaf(xv, wp[i], acc[i]);
        }
      }
    }
  }
  float* pp = partial + ((size_t)sk * COUT + coutBase) * NPOS + tid;
#pragma unroll
  for (int i = 0; i < CB; ++i) pp[(size_t)i * NPOS] = acc[i];
}

// ---------------------------------------------------------------------------
// Reduce split-K partials + bias + ReLU -> NCDHW output
// ---------------------------------------------------------------------------
template <int COUT, int SK, int NPOS>
__global__ __launch_bounds__(256) void reduce_bnrelu(
    const float* __restrict__ partial, const float* __restrict__ bias,
    float* __restrict__ out) {
  constexpr int OS = NPOS / 2;  // per-batch spatial
  int idx = blockIdx.x * 256 + threadIdx.x;  // over 2*COUT*OS
  int s = idx & (OS - 1);
  int t = idx / OS;            // b*COUT + cout
  int cout = t & (COUT - 1);
  int b = t / COUT;
  int pos = b * OS + s;
  float sum = 0.f;
#pragma unroll
  for (int k = 0; k < SK; ++k)
    sum += partial[((size_t)k * COUT + cout) * NPOS + pos];
  out[idx] = fmaxf(sum + bias[cout], 0.f);
}

// ---------------------------------------------------------------------------
// Final 1x1x1 conv: h5[2,512,4,4,4] x w[256,512] -> out[2,256,4,4,4]
// block = 128 threads (b,s); blockIdx.x = cout
// ---------------------------------------------------------------------------
__global__ __launch_bounds__(128) void conv1x1_out(
    const float* __restrict__ h5, const float* __restrict__ w,
    float* __restrict__ out) {
  int cout = blockIdx.x;
  int b = threadIdx.x >> 6;
  int s = threadIdx.x & 63;
  const float* ip = h5 + (size_t)b * 512 * 64 + s;
  const float* wp = w + (size_t)cout * 512;
  float acc = 0.f;
#pragma unroll 8
  for (int c = 0; c < 512; ++c) acc = fmaf(ip[(size_t)c * 64], wp[c], acc);
  out[((size_t)b * 256 + cout) * 64 + s] = acc;
}

// ---------------------------------------------------------------------------
extern "C" void kernel_launch(void* const* d_in, const int* in_sizes, int n_in,
                              void* d_out, int out_size, void* d_ws,
                              size_t ws_size, hipStream_t stream) {
  const float* x = (const float*)d_in[0];
  const float* w1 = (const float*)d_in[1];
  const float* g1 = (const float*)d_in[2];
  const float* bb1 = (const float*)d_in[3];
  const float* m1 = (const float*)d_in[4];
  const float* v1 = (const float*)d_in[5];
  const float* w2 = (const float*)d_in[6];
  const float* g2 = (const float*)d_in[7];
  const float* bb2 = (const float*)d_in[8];
  const float* m2 = (const float*)d_in[9];
  const float* v2 = (const float*)d_in[10];
  const float* w3 = (const float*)d_in[11];
  const float* g3 = (const float*)d_in[12];
  const float* bb3 = (const float*)d_in[13];
  const float* m3 = (const float*)d_in[14];
  const float* v3 = (const float*)d_in[15];
  const float* w4 = (const float*)d_in[16];
  const float* g4 = (const float*)d_in[17];
  const float* bb4 = (const float*)d_in[18];
  const float* m4 = (const float*)d_in[19];
  const float* v4 = (const float*)d_in[20];
  const float* w5 = (const float*)d_in[21];
  const float* g5 = (const float*)d_in[22];
  const float* bb5 = (const float*)d_in[23];
  const float* m5 = (const float*)d_in[24];
  const float* v5 = (const float*)d_in[25];
  const float* w_out = (const float*)d_in[26];

  float* ws = (float*)d_ws;
  size_t o = 0;
  float* wt1 = ws + o; o += (size_t)32 * 4 * 27;     // 3456
  float* wt2 = ws + o; o += (size_t)64 * 32 * 27;    // 55296
  float* wt3 = ws + o; o += (size_t)128 * 64 * 27;   // 221184
  float* wt4 = ws + o; o += (size_t)256 * 128 * 27;  // 884736
  float* wt5 = ws + o; o += (size_t)512 * 256 * 27;  // 3538944
  float* bs1 = ws + o; o += 32;
  float* bs2 = ws + o; o += 64;
  float* bs3 = ws + o; o += 128;
  float* bs4 = ws + o; o += 256;
  float* bs5 = ws + o; o += 512;
  o = (o + 63) & ~(size_t)63;
  float* A = ws + o; o += 16777216;  // region A (67.1 MB)
  float* B = ws + o; o += 4194304;   // region B (16.8 MB)
  // lifetime-based aliasing inside A/B:
  float* h1 = A;                               // stage1 out  [2,32,64^3]
  float* h2 = B;                               // stage2 out  [2,64,32^3]
  float* h3 = A;                               // stage3 out  [2,128,16^3] (h1 dead)
  float* p4 = A + 1048576;                     // splitK partials stage4 (8*262144)
  float* h4 = B;                               // stage4 out  (h2 dead)
  float* p5 = A + 1048576 + 2097152;           // splitK partials stage5 (16*65536)
  float* h5 = A + 1048576 + 2097152 + 1048576; // stage5 out
  (void)ws_size; (void)in_sizes; (void)n_in; (void)out_size;

  // --- weight repack + BN fold ---
  repack_kernel<4, 32><<<(32 * 4 * 27 + 255) / 256, 256, 0, stream>>>(
      w1, g1, bb1, m1, v1, wt1, bs1);
  repack_kernel<32, 64><<<(64 * 32 * 27 + 255) / 256, 256, 0, stream>>>(
      w2, g2, bb2, m2, v2, wt2, bs2);
  repack_kernel<64, 128><<<(128 * 64 * 27 + 255) / 256, 256, 0, stream>>>(
      w3, g3, bb3, m3, v3, wt3, bs3);
  repack_kernel<128, 256><<<(256 * 128 * 27 + 255) / 256, 256, 0, stream>>>(
      w4, g4, bb4, m4, v4, wt4, bs4);
  repack_kernel<256, 512><<<(512 * 256 * 27 + 255) / 256, 256, 0, stream>>>(
      w5, g5, bb5, m5, v5, wt5, bs5);

  // --- stage 1: [2,4,128^3] -> [2,32,64^3] ---
  conv_s2_bnrelu<4, 32, 32, 64, 256>
      <<<dim3(2048, 1), 256, 0, stream>>>(x, wt1, bs1, h1);
  // --- stage 2: [2,32,64^3] -> [2,64,32^3] ---
  conv_s2_bnrelu<32, 64, 16, 32, 256>
      <<<dim3(256, 4), 256, 0, stream>>>(h1, wt2, bs2, h2);
  // --- stage 3: [2,64,32^3] -> [2,128,16^3] ---
  conv_s2_bnrelu<64, 128, 8, 16, 256>
      <<<dim3(32, 16), 256, 0, stream>>>(h2, wt3, bs3, h3);
  // --- stage 4 (split-K): [2,128,16^3] -> [2,256,8^3] ---
  conv_s2_splitk<128, 256, 8, 8, 8, 256>
      <<<dim3(4, 32, 8), 256, 0, stream>>>(h3, wt4, p4);
  reduce_bnrelu<256, 8, 1024><<<1024, 256, 0, stream>>>(p4, bs4, h4);
  // --- stage 5 (split-K): [2,256,8^3] -> [2,512,4^3] ---
  conv_s2_splitk<256, 512, 8, 4, 16, 128>
      <<<dim3(1, 64, 16), 128, 0, stream>>>(h4, wt5, p5);
  reduce_bnrelu<512, 16, 128><<<256, 256, 0, stream>>>(p5, bs5, h5);
  // --- final 1x1x1 conv ---
  conv1x1_out<<<256, 128, 0, stream>>>(h5, w_out, (float*)d_out);
}

// Round 3
// 472.342 us; speedup vs baseline: 1.3185x; 1.3185x over previous
//
#include <hip/hip_runtime.h>

static constexpr float kEps = 1e-5f;

using bf16x8 = __attribute__((ext_vector_type(8))) short;
using f32x4 = __attribute__((ext_vector_type(4))) float;

constexpr int ilog2(int n) { return n <= 1 ? 0 : 1 + ilog2(n / 2); }

// round-to-nearest-even f32 -> bf16 bits
__device__ inline unsigned bf_rne(float v) {
  unsigned u = __float_as_uint(v);
  return (u + 0x7FFFu + ((u >> 16) & 1u)) >> 16;
}
// split f32 into bf16 hi + bf16 lo (v ~= hi + lo)
__device__ inline void split_bf(float v, unsigned short& h, unsigned short& l) {
  unsigned hb = bf_rne(v);
  h = (unsigned short)hb;
  float hf = __uint_as_float(hb << 16);
  l = (unsigned short)bf_rne(v - hf);
}

// ---------------------------------------------------------------------------
// Stage-1 weight repack (fp32, old layout): wT[(cin*27+k)*COUT+cout]
// ---------------------------------------------------------------------------
template <int CIN, int COUT>
__global__ __launch_bounds__(256) void repack_kernel(
    const float* __restrict__ w, const float* __restrict__ g,
    const float* __restrict__ b, const float* __restrict__ m,
    const float* __restrict__ v, float* __restrict__ wT,
    float* __restrict__ bias) {
  int idx = blockIdx.x * 256 + threadIdx.x;
  constexpr int total = COUT * CIN * 27;
  if (idx < COUT) {
    float inv = g[idx] * rsqrtf(v[idx] + kEps);
    bias[idx] = b[idx] - m[idx] * inv;
  }
  if (idx < total) {
    int cout = idx % COUT;
    int ck = idx / COUT;
    int cin = ck / 27;
    int k = ck % 27;
    float inv = g[cout] * rsqrtf(v[cout] + kEps);
    wT[idx] = w[(cout * CIN + cin) * 27 + k] * inv;
  }
}

// ---------------------------------------------------------------------------
// MFMA-stage weight repack: wh/wl[tap][cout][cin] (bf16 hi/lo), BN folded.
// ---------------------------------------------------------------------------
template <int CIN, int COUT>
__global__ __launch_bounds__(256) void repack_bf16(
    const float* __restrict__ w, const float* __restrict__ g,
    const float* __restrict__ b, const float* __restrict__ m,
    const float* __restrict__ v, unsigned short* __restrict__ wh,
    unsigned short* __restrict__ wl, float* __restrict__ bias) {
  int idx = blockIdx.x * 256 + threadIdx.x;
  constexpr int total = 27 * COUT * CIN;
  constexpr int LC = ilog2(CIN), LO = ilog2(COUT);
  if (idx < COUT) {
    float inv = g[idx] * rsqrtf(v[idx] + kEps);
    bias[idx] = b[idx] - m[idx] * inv;
  }
  if (idx < total) {
    int ci = idx & (CIN - 1);
    int t = idx >> LC;
    int co = t & (COUT - 1);
    int tap = t >> LO;
    float inv = g[co] * rsqrtf(v[co] + kEps);
    float val = w[((size_t)co * CIN + ci) * 27 + tap] * inv;
    unsigned short h, l;
    split_bf(val, h, l);
    wh[idx] = h;
    wl[idx] = l;
  }
}

// w_out [256,512] -> woutT [512][256]
__global__ __launch_bounds__(256) void repack_wout(const float* __restrict__ w,
                                                   float* __restrict__ wt) {
  int idx = blockIdx.x * 256 + threadIdx.x;  // = c*256 + co
  int co = idx & 255;
  int c = idx >> 8;
  wt[idx] = w[(size_t)co * 512 + c];
}

// ---------------------------------------------------------------------------
// Stage 1: fp32 direct conv (cin=4), outputs channels-last bf16 hi/lo.
// ---------------------------------------------------------------------------
__global__ __launch_bounds__(256) void conv1_direct(
    const float* __restrict__ in, const float* __restrict__ wT,
    const float* __restrict__ bias, unsigned short* __restrict__ outh,
    unsigned short* __restrict__ outl) {
  constexpr int DI = 128, CIN = 4, COUT = 32;
  int tid = blockIdx.x * 256 + threadIdx.x;
  int x = tid & 63;
  int t = tid >> 6;
  int y = t & 63;
  t >>= 6;
  int z = t & 63;
  int bb = t >> 6;

  float acc[COUT];
#pragma unroll
  for (int i = 0; i < COUT; ++i) acc[i] = 0.f;

  const float* inb = in + (size_t)bb * CIN * DI * DI * DI;
  for (int cin = 0; cin < CIN; ++cin) {
    const float* inc = inb + (size_t)cin * DI * DI * DI;
#pragma unroll
    for (int kz = 0; kz < 3; ++kz) {
      int iz = 2 * z + kz - 1;
      if (iz < 0) continue;
#pragma unroll
      for (int ky = 0; ky < 3; ++ky) {
        int iy = 2 * y + ky - 1;
        if (iy < 0) continue;
        const float* row = inc + ((size_t)iz * DI + iy) * DI;
#pragma unroll
        for (int kx = 0; kx < 3; ++kx) {
          int ix = 2 * x + kx - 1;
          float xv = (ix >= 0) ? row[ix] : 0.f;
          const float* wp = wT + ((size_t)cin * 27 + (kz * 3 + ky) * 3 + kx) * COUT;
#pragma unroll
          for (int i = 0; i < COUT; ++i) acc[i] = fmaf(xv, wp[i], acc[i]);
        }
      }
    }
  }
  size_t op = (size_t)tid * COUT;
#pragma unroll
  for (int i = 0; i < COUT; ++i) {
    float r = fmaxf(acc[i] + bias[i], 0.f);
    unsigned short h, l;
    split_bf(r, h, l);
    outh[op + i] = h;
    outl[op + i] = l;
  }
}

// ---------------------------------------------------------------------------
// MFMA implicit-GEMM conv (3x3x3 stride-2 pad-1), channels-last hi/lo bf16.
// 3-product split: acc += Ah*Bh + Ah*Bl + Al*Bh  (fp32 accumulate).
// Block = 4 waves, each wave: 16(M) x 64(N) tile via 4 n-quads.
// mfma_f32_16x16x32_bf16 layouts: A lane: m=lane&15, k=(lane>>4)*8+j;
// B lane: n=lane&15, k=(lane>>4)*8+j; D lane: n=lane&15, m=(lane>>4)*4+reg.
// SK>1: split over taps (27/SK per block), fp32 partials to ws.
// ---------------------------------------------------------------------------
template <int CIN, int COUT, int DO, int SK>
__global__ __launch_bounds__(256) void conv_mfma(
    const unsigned short* __restrict__ inh, const unsigned short* __restrict__ inl,
    const unsigned short* __restrict__ wh, const unsigned short* __restrict__ wl,
    const float* __restrict__ bias, unsigned short* __restrict__ outh,
    unsigned short* __restrict__ outl, float* __restrict__ partial) {
  constexpr int DI = DO * 2;
  constexpr int M = 2 * DO * DO * DO;
  constexpr int TAPS = 27 / SK;
  constexpr int KCPT = CIN / 32;
  constexpr int LD = ilog2(DO);

  const int lane = threadIdx.x & 63;
  const int wv = threadIdx.x >> 6;
  const int mBase = blockIdx.x * 64 + wv * 16;
  const int nBase = blockIdx.y * 64;
  const int skid = blockIdx.z;
  const int mlane = lane & 15;
  const int kgrp = lane >> 4;

  const int m = mBase + mlane;
  const int x = m & (DO - 1);
  const int y = (m >> LD) & (DO - 1);
  const int z = (m >> (2 * LD)) & (DO - 1);
  const int b = m >> (3 * LD);

  f32x4 acc[4] = {{0.f, 0.f, 0.f, 0.f},
                  {0.f, 0.f, 0.f, 0.f},
                  {0.f, 0.f, 0.f, 0.f},
                  {0.f, 0.f, 0.f, 0.f}};

  for (int tp = 0; tp < TAPS; ++tp) {
    const int tap = skid * TAPS + tp;
    const int kz = tap / 9;
    const int kr = tap - kz * 9;
    const int ky = kr / 3;
    const int kx = kr - ky * 3;
    const int iz = 2 * z + kz - 1;
    const int iy = 2 * y + ky - 1;
    const int ix = 2 * x + kx - 1;
    const bool valid = (iz >= 0) && (iy >= 0) && (ix >= 0);
    const size_t aoff =
        ((((size_t)b * DI + iz) * DI + iy) * DI + ix) * CIN + kgrp * 8;
    const unsigned short* ah = inh + aoff;
    const unsigned short* al = inl + aoff;
    const size_t woff = (size_t)tap * COUT * CIN + (size_t)(nBase + mlane) * CIN + kgrp * 8;
    const unsigned short* wbh = wh + woff;
    const unsigned short* wbl = wl + woff;
#pragma unroll
    for (int kc = 0; kc < KCPT; ++kc) {
      bf16x8 Ah = {0, 0, 0, 0, 0, 0, 0, 0};
      bf16x8 Al = {0, 0, 0, 0, 0, 0, 0, 0};
      if (valid) {
        Ah = *reinterpret_cast<const bf16x8*>(ah + kc * 32);
        Al = *reinterpret_cast<const bf16x8*>(al + kc * 32);
      }
#pragma unroll
      for (int nq = 0; nq < 4; ++nq) {
        bf16x8 Bh = *reinterpret_cast<const bf16x8*>(wbh + (size_t)nq * 16 * CIN + kc * 32);
        bf16x8 Bl = *reinterpret_cast<const bf16x8*>(wbl + (size_t)nq * 16 * CIN + kc * 32);
        acc[nq] = __builtin_amdgcn_mfma_f32_16x16x32_bf16(Ah, Bh, acc[nq], 0, 0, 0);
        acc[nq] = __builtin_amdgcn_mfma_f32_16x16x32_bf16(Ah, Bl, acc[nq], 0, 0, 0);
        acc[nq] = __builtin_amdgcn_mfma_f32_16x16x32_bf16(Al, Bh, acc[nq], 0, 0, 0);
      }
    }
  }

  if constexpr (SK == 1) {
#pragma unroll
    for (int nq = 0; nq < 4; ++nq) {
      const int n = nBase + nq * 16 + mlane;
      const float bv = bias[n];
#pragma unroll
      for (int r = 0; r < 4; ++r) {
        const int mrow = mBase + kgrp * 4 + r;
        float vv = fmaxf(acc[nq][r] + bv, 0.f);
        unsigned short h, l;
        split_bf(vv, h, l);
        outh[(size_t)mrow * COUT + n] = h;
        outl[(size_t)mrow * COUT + n] = l;
      }
    }
  } else {
#pragma unroll
    for (int nq = 0; nq < 4; ++nq) {
      const int n = nBase + nq * 16 + mlane;
#pragma unroll
      for (int r = 0; r < 4; ++r) {
        const int mrow = mBase + kgrp * 4 + r;
        partial[((size_t)skid * M + mrow) * COUT + n] = acc[nq][r];
      }
    }
  }
}

// ---------------------------------------------------------------------------
// Reduce split-K fp32 partials + bias + ReLU -> bf16 hi/lo (or fp32) out.
// ---------------------------------------------------------------------------
template <int COUT, int SK, int M, bool F32OUT>
__global__ __launch_bounds__(256) void reduce_split(
    const float* __restrict__ partial, const float* __restrict__ bias,
    unsigned short* __restrict__ oh, unsigned short* __restrict__ ol,
    float* __restrict__ of) {
  int idx = blockIdx.x * 256 + threadIdx.x;  // < M*COUT, idx = mrow*COUT+n
  int n = idx & (COUT - 1);
  float s = 0.f;
#pragma unroll
  for (int k = 0; k < SK; ++k) s += partial[(size_t)k * M * COUT + idx];
  float v = fmaxf(s + bias[n], 0.f);
  if constexpr (F32OUT) {
    of[idx] = v;
  } else {
    unsigned short h, l;
    split_bf(v, h, l);
    oh[idx] = h;
    ol[idx] = l;
  }
}

// ---------------------------------------------------------------------------
// Final 1x1x1 conv: h5 [128][512] fp32 x woutT [512][256] -> out NCDHW
// ---------------------------------------------------------------------------
__global__ __launch_bounds__(256) void conv1x1_final(
    const float* __restrict__ h5, const float* __restrict__ wt,
    float* __restrict__ out) {
  int p = blockIdx.x;        // 0..127 = b*64 + s
  int co = threadIdx.x;      // 0..255
  int b = p >> 6;
  int s = p & 63;
  const float* hp = h5 + (size_t)p * 512;
  float acc = 0.f;
#pragma unroll 8
  for (int c = 0; c < 512; ++c) acc = fmaf(hp[c], wt[(size_t)c * 256 + co], acc);
  out[((size_t)b * 256 + co) * 64 + s] = acc;
}

// ---------------------------------------------------------------------------
extern "C" void kernel_launch(void* const* d_in, const int* in_sizes, int n_in,
                              void* d_out, int out_size, void* d_ws,
                              size_t ws_size, hipStream_t stream) {
  const float* x = (const float*)d_in[0];
  const float* w1 = (const float*)d_in[1];
  const float* g1 = (const float*)d_in[2];
  const float* bb1 = (const float*)d_in[3];
  const float* m1 = (const float*)d_in[4];
  const float* v1 = (const float*)d_in[5];
  const float* w2 = (const float*)d_in[6];
  const float* g2 = (const float*)d_in[7];
  const float* bb2 = (const float*)d_in[8];
  const float* m2 = (const float*)d_in[9];
  const float* v2 = (const float*)d_in[10];
  const float* w3 = (const float*)d_in[11];
  const float* g3 = (const float*)d_in[12];
  const float* bb3 = (const float*)d_in[13];
  const float* m3 = (const float*)d_in[14];
  const float* v3 = (const float*)d_in[15];
  const float* w4 = (const float*)d_in[16];
  const float* g4 = (const float*)d_in[17];
  const float* bb4 = (const float*)d_in[18];
  const float* m4 = (const float*)d_in[19];
  const float* v4 = (const float*)d_in[20];
  const float* w5 = (const float*)d_in[21];
  const float* g5 = (const float*)d_in[22];
  const float* bb5 = (const float*)d_in[23];
  const float* m5 = (const float*)d_in[24];
  const float* v5 = (const float*)d_in[25];
  const float* w_out = (const float*)d_in[26];
  (void)in_sizes; (void)n_in; (void)out_size; (void)ws_size;

  char* base = (char*)d_ws;
  size_t off = 0;
  auto take = [&](size_t bytes) {
    char* p = base + off;
    off = (off + bytes + 255) & ~(size_t)255;
    return p;
  };
  float* wt1 = (float*)take(3456 * 4);
  unsigned short* w2h = (unsigned short*)take(55296 * 2);
  unsigned short* w2l = (unsigned short*)take(55296 * 2);
  unsigned short* w3h = (unsigned short*)take(221184 * 2);
  unsigned short* w3l = (unsigned short*)take(221184 * 2);
  unsigned short* w4h = (unsigned short*)take(884736 * 2);
  unsigned short* w4l = (unsigned short*)take(884736 * 2);
  unsigned short* w5h = (unsigned short*)take(3538944 * 2);
  unsigned short* w5l = (unsigned short*)take(3538944 * 2);
  float* woutT = (float*)take(131072 * 4);
  float* bs1 = (float*)take(32 * 4);
  float* bs2 = (float*)take(64 * 4);
  float* bs3 = (float*)take(128 * 4);
  float* bs4 = (float*)take(256 * 4);
  float* bs5 = (float*)take(512 * 4);
  // h1 region (67.1 MB): h1h+h1l live only for stages 1-2; afterwards aliased
  // by split-K partials (@0, max 12.6 MB) and h3/h4/h5 (@16 MB+).
  unsigned short* h1h = (unsigned short*)take((size_t)16777216 * 2);
  unsigned short* h1l = (unsigned short*)take((size_t)16777216 * 2);
  unsigned short* h2h = (unsigned short*)take((size_t)4194304 * 2);
  unsigned short* h2l = (unsigned short*)take((size_t)4194304 * 2);

  char* AR = (char*)h1h;
  float* p3 = (float*)AR;                       // 3*8192*128*4  = 12.58 MB
  float* p4 = (float*)AR;                       // 9*1024*256*4  =  9.44 MB (p3 dead)
  float* p5 = (float*)AR;                       // 9*128*512*4   =  2.36 MB (p4 dead)
  char* AR2 = AR + ((size_t)16 << 20);
  unsigned short* h3h = (unsigned short*)AR2;                       // 2.10 MB
  unsigned short* h3l = (unsigned short*)(AR2 + 2097152);           // 2.10 MB
  unsigned short* h4h = (unsigned short*)(AR2 + 2 * 2097152);       // 0.52 MB
  unsigned short* h4l = (unsigned short*)(AR2 + 2 * 2097152 + 524288);
  float* h5 = (float*)(AR2 + 2 * 2097152 + 2 * 524288);             // 0.26 MB

  // --- weight repacks ---
  repack_kernel<4, 32><<<(3456 + 255) / 256, 256, 0, stream>>>(
      w1, g1, bb1, m1, v1, wt1, bs1);
  repack_bf16<32, 64><<<(55296 + 255) / 256, 256, 0, stream>>>(
      w2, g2, bb2, m2, v2, w2h, w2l, bs2);
  repack_bf16<64, 128><<<(221184 + 255) / 256, 256, 0, stream>>>(
      w3, g3, bb3, m3, v3, w3h, w3l, bs3);
  repack_bf16<128, 256><<<(884736 + 255) / 256, 256, 0, stream>>>(
      w4, g4, bb4, m4, v4, w4h, w4l, bs4);
  repack_bf16<256, 512><<<(3538944 + 255) / 256, 256, 0, stream>>>(
      w5, g5, bb5, m5, v5, w5h, w5l, bs5);
  repack_wout<<<512, 256, 0, stream>>>(w_out, woutT);

  // --- stage 1: fp32 direct, [2,4,128^3] -> cl hi/lo [2*64^3][32] ---
  conv1_direct<<<2048, 256, 0, stream>>>(x, wt1, bs1, h1h, h1l);

  // --- stage 2: MFMA [2*32^3][64], SK=1, fused epilogue ---
  conv_mfma<32, 64, 32, 1><<<dim3(1024, 1, 1), 256, 0, stream>>>(
      h1h, h1l, w2h, w2l, bs2, h2h, h2l, nullptr);

  // --- stage 3: MFMA [2*16^3][128], SK=3 ---
  conv_mfma<64, 128, 16, 3><<<dim3(128, 2, 3), 256, 0, stream>>>(
      h2h, h2l, w3h, w3l, bs3, nullptr, nullptr, p3);
  reduce_split<128, 3, 8192, false><<<4096, 256, 0, stream>>>(
      p3, bs3, h3h, h3l, nullptr);

  // --- stage 4: MFMA [2*8^3][256], SK=9 ---
  conv_mfma<128, 256, 8, 9><<<dim3(16, 4, 9), 256, 0, stream>>>(
      h3h, h3l, w4h, w4l, bs4, nullptr, nullptr, p4);
  reduce_split<256, 9, 1024, false><<<1024, 256, 0, stream>>>(
      p4, bs4, h4h, h4l, nullptr);

  // --- stage 5: MFMA [2*4^3][512], SK=9, fp32 out ---
  conv_mfma<256, 512, 4, 9><<<dim3(2, 8, 9), 256, 0, stream>>>(
      h4h, h4l, w5h, w5l, bs5, nullptr, nullptr, p5);
  reduce_split<512, 9, 128, true><<<256, 256, 0, stream>>>(
      p5, bs5, nullptr, nullptr, h5);

  // --- final 1x1x1 conv ---
  conv1x1_final<<<128, 256, 0, stream>>>(h5, woutT, (float*)d_out);
}

// Round 4
// 421.575 us; speedup vs baseline: 1.4773x; 1.1204x over previous
//
#include <hip/hip_runtime.h>

static constexpr float kEps = 1e-5f;

using bf16x8 = __attribute__((ext_vector_type(8))) short;
using f32x4 = __attribute__((ext_vector_type(4))) float;
typedef unsigned short ushort_t;

constexpr int ilog2(int n) { return n <= 1 ? 0 : 1 + ilog2(n / 2); }

// round-to-nearest-even f32 -> bf16 bits
__device__ inline unsigned bf_rne(float v) {
  unsigned u = __float_as_uint(v);
  return (u + 0x7FFFu + ((u >> 16) & 1u)) >> 16;
}
// split f32 into bf16 hi + bf16 lo (v ~= hi + lo)
__device__ inline void split_bf(float v, unsigned short& h, unsigned short& l) {
  unsigned hb = bf_rne(v);
  h = (unsigned short)hb;
  float hf = __uint_as_float(hb << 16);
  l = (unsigned short)bf_rne(v - hf);
}

// ---------------------------------------------------------------------------
// Stage-1 weight repack (fp32): wT[(cin*27+k)*COUT+cout]
// ---------------------------------------------------------------------------
template <int CIN, int COUT>
__global__ __launch_bounds__(256) void repack_kernel(
    const float* __restrict__ w, const float* __restrict__ g,
    const float* __restrict__ b, const float* __restrict__ m,
    const float* __restrict__ v, float* __restrict__ wT,
    float* __restrict__ bias) {
  int idx = blockIdx.x * 256 + threadIdx.x;
  constexpr int total = COUT * CIN * 27;
  if (idx < COUT) {
    float inv = g[idx] * rsqrtf(v[idx] + kEps);
    bias[idx] = b[idx] - m[idx] * inv;
  }
  if (idx < total) {
    int cout = idx % COUT;
    int ck = idx / COUT;
    int cin = ck / 27;
    int k = ck % 27;
    float inv = g[cout] * rsqrtf(v[cout] + kEps);
    wT[idx] = w[(cout * CIN + cin) * 27 + k] * inv;
  }
}

// ---------------------------------------------------------------------------
// MFMA-stage weight repack: wh/wl[tap][cout][cin] (bf16 hi/lo), BN folded.
// ---------------------------------------------------------------------------
template <int CIN, int COUT>
__global__ __launch_bounds__(256) void repack_bf16(
    const float* __restrict__ w, const float* __restrict__ g,
    const float* __restrict__ b, const float* __restrict__ m,
    const float* __restrict__ v, unsigned short* __restrict__ wh,
    unsigned short* __restrict__ wl, float* __restrict__ bias) {
  int idx = blockIdx.x * 256 + threadIdx.x;
  constexpr int total = 27 * COUT * CIN;
  constexpr int LC = ilog2(CIN), LO = ilog2(COUT);
  if (idx < COUT) {
    float inv = g[idx] * rsqrtf(v[idx] + kEps);
    bias[idx] = b[idx] - m[idx] * inv;
  }
  if (idx < total) {
    int ci = idx & (CIN - 1);
    int t = idx >> LC;
    int co = t & (COUT - 1);
    int tap = t >> LO;
    float inv = g[co] * rsqrtf(v[co] + kEps);
    float val = w[((size_t)co * CIN + ci) * 27 + tap] * inv;
    unsigned short h, l;
    split_bf(val, h, l);
    wh[idx] = h;
    wl[idx] = l;
  }
}

// w_out [256,512] -> woutT [512][256]
__global__ __launch_bounds__(256) void repack_wout(const float* __restrict__ w,
                                                   float* __restrict__ wt) {
  int idx = blockIdx.x * 256 + threadIdx.x;  // = c*256 + co
  int co = idx & 255;
  int c = idx >> 8;
  wt[idx] = w[(size_t)co * 512 + c];
}

// ---------------------------------------------------------------------------
// Stage 1: fp32 direct conv (cin=4) -> parity-split channels-last bf16 hi/lo.
// Output parity grid: [b][pz][py][px][32^3][32]
// ---------------------------------------------------------------------------
__global__ __launch_bounds__(256) void conv1_direct(
    const float* __restrict__ in, const float* __restrict__ wT,
    const float* __restrict__ bias, unsigned short* __restrict__ outh,
    unsigned short* __restrict__ outl) {
  constexpr int DI = 128, CIN = 4, COUT = 32;
  int tid = blockIdx.x * 256 + threadIdx.x;
  int x = tid & 63;
  int t = tid >> 6;
  int y = t & 63;
  t >>= 6;
  int z = t & 63;
  int bb = t >> 6;

  float acc[COUT];
#pragma unroll
  for (int i = 0; i < COUT; ++i) acc[i] = 0.f;

  const float* inb = in + (size_t)bb * CIN * DI * DI * DI;
  for (int cin = 0; cin < CIN; ++cin) {
    const float* inc = inb + (size_t)cin * DI * DI * DI;
#pragma unroll
    for (int kz = 0; kz < 3; ++kz) {
      int iz = 2 * z + kz - 1;
      if (iz < 0) continue;
#pragma unroll
      for (int ky = 0; ky < 3; ++ky) {
        int iy = 2 * y + ky - 1;
        if (iy < 0) continue;
        const float* row = inc + ((size_t)iz * DI + iy) * DI;
#pragma unroll
        for (int kx = 0; kx < 3; ++kx) {
          int ix = 2 * x + kx - 1;
          float xv = (ix >= 0) ? row[ix] : 0.f;
          const float* wp = wT + ((size_t)cin * 27 + (kz * 3 + ky) * 3 + kx) * COUT;
#pragma unroll
          for (int i = 0; i < COUT; ++i) acc[i] = fmaf(xv, wp[i], acc[i]);
        }
      }
    }
  }
  int pidx = (z & 1) * 4 + (y & 1) * 2 + (x & 1);
  size_t sub = (((size_t)(z >> 1) * 32) + (y >> 1)) * 32 + (x >> 1);
  size_t op = (((size_t)bb * 8 + pidx) * 32768 + sub) * COUT;
#pragma unroll
  for (int i = 0; i < COUT; ++i) {
    float r = fmaxf(acc[i] + bias[i], 0.f);
    unsigned short h, l;
    split_bf(r, h, l);
    outh[op + i] = h;
    outl[op + i] = l;
  }
}

// ---------------------------------------------------------------------------
// MFMA implicit-GEMM conv (3x3x3 stride-2 pad-1) on parity-split input.
// Input: [b][pz][py][px][DO^3][CIN] (sub-grid dim == this stage's DO).
// Tap (kz,ky,kx): p = (k!=1), d = (k==0); reads sub-grid p at coord-d.
// => every tap's A-load is a contiguous shifted block (coalesced).
// 3-product split: acc += Ah*Bh + Ah*Bl + Al*Bh (fp32 accumulate).
// Block = 4 waves; wave tile = (MREP*16) M x 64 N.
// SK>1: taps split across blockIdx.z, fp32 partials to ws.
// SK==1: fused bias+ReLU epilogue, writes parity-split for next stage.
// ---------------------------------------------------------------------------
template <int CIN, int COUT, int DO, int SK, int MREP>
__global__ __launch_bounds__(256) void conv_mfma(
    const unsigned short* __restrict__ inh, const unsigned short* __restrict__ inl,
    const unsigned short* __restrict__ wh, const unsigned short* __restrict__ wl,
    const float* __restrict__ bias, unsigned short* __restrict__ outh,
    unsigned short* __restrict__ outl, float* __restrict__ partial) {
  constexpr int M = 2 * DO * DO * DO;
  constexpr int TAPS = 27 / SK;
  constexpr int KCPT = CIN / 32;
  constexpr int LD = ilog2(DO);
  constexpr int SUB = DO * DO * DO;

  const int lane = threadIdx.x & 63;
  const int wv = threadIdx.x >> 6;
  const int mWave = (blockIdx.x * 4 + wv) * (MREP * 16);
  const int nBase = blockIdx.y * 64;
  const int skid = blockIdx.z;
  const int mlane = lane & 15;
  const int kgrp = lane >> 4;

  int xf[MREP], yf[MREP], zf[MREP], bf_[MREP];
#pragma unroll
  for (int f = 0; f < MREP; ++f) {
    int m = mWave + f * 16 + mlane;
    xf[f] = m & (DO - 1);
    yf[f] = (m >> LD) & (DO - 1);
    zf[f] = (m >> (2 * LD)) & (DO - 1);
    bf_[f] = m >> (3 * LD);
  }

  f32x4 acc[MREP][4];
#pragma unroll
  for (int f = 0; f < MREP; ++f)
#pragma unroll
    for (int q = 0; q < 4; ++q) acc[f][q] = (f32x4){0.f, 0.f, 0.f, 0.f};

  for (int tp = 0; tp < TAPS; ++tp) {
    const int tap = skid * TAPS + tp;
    const int kz = tap / 9;
    const int kr = tap - kz * 9;
    const int ky = kr / 3;
    const int kx = kr - ky * 3;
    const int pidx = (kz != 1) * 4 + (ky != 1) * 2 + (kx != 1);
    const int dz = (kz == 0), dy = (ky == 0), dx = (kx == 0);

    const size_t woff = (size_t)tap * COUT * CIN + (size_t)(nBase + mlane) * CIN + kgrp * 8;
    const unsigned short* wbh = wh + woff;
    const unsigned short* wbl = wl + woff;

    long long aoff[MREP];
    bool valid[MREP];
#pragma unroll
    for (int f = 0; f < MREP; ++f) {
      int sx = xf[f] - dx, sy = yf[f] - dy, sz = zf[f] - dz;
      valid[f] = ((sx | sy | sz) >= 0);
      aoff[f] = ((long long)(bf_[f] * 8 + pidx) * SUB + (sz * DO + sy) * DO + sx) * CIN +
                kgrp * 8;
    }

#pragma unroll
    for (int kc = 0; kc < KCPT; ++kc) {
      bf16x8 Ah[MREP], Al[MREP];
#pragma unroll
      for (int f = 0; f < MREP; ++f) {
        Ah[f] = (bf16x8){0, 0, 0, 0, 0, 0, 0, 0};
        Al[f] = (bf16x8){0, 0, 0, 0, 0, 0, 0, 0};
        if (valid[f]) {
          Ah[f] = *reinterpret_cast<const bf16x8*>(inh + aoff[f] + kc * 32);
          Al[f] = *reinterpret_cast<const bf16x8*>(inl + aoff[f] + kc * 32);
        }
      }
#pragma unroll
      for (int nq = 0; nq < 4; ++nq) {
        bf16x8 Bh = *reinterpret_cast<const bf16x8*>(wbh + (size_t)nq * 16 * CIN + kc * 32);
        bf16x8 Bl = *reinterpret_cast<const bf16x8*>(wbl + (size_t)nq * 16 * CIN + kc * 32);
#pragma unroll
        for (int f = 0; f < MREP; ++f) {
          acc[f][nq] = __builtin_amdgcn_mfma_f32_16x16x32_bf16(Ah[f], Bh, acc[f][nq], 0, 0, 0);
          acc[f][nq] = __builtin_amdgcn_mfma_f32_16x16x32_bf16(Ah[f], Bl, acc[f][nq], 0, 0, 0);
          acc[f][nq] = __builtin_amdgcn_mfma_f32_16x16x32_bf16(Al[f], Bh, acc[f][nq], 0, 0, 0);
        }
      }
    }
  }

  if constexpr (SK == 1) {
    constexpr int HD = DO / 2;
#pragma unroll
    for (int f = 0; f < MREP; ++f) {
#pragma unroll
      for (int nq = 0; nq < 4; ++nq) {
        const int n = nBase + nq * 16 + mlane;
        const float bv = bias[n];
#pragma unroll
        for (int r = 0; r < 4; ++r) {
          const int mrow = mWave + f * 16 + kgrp * 4 + r;
          const int ox = mrow & (DO - 1);
          const int oy = (mrow >> LD) & (DO - 1);
          const int oz = (mrow >> (2 * LD)) & (DO - 1);
          const int ob = mrow >> (3 * LD);
          const int pp = (oz & 1) * 4 + (oy & 1) * 2 + (ox & 1);
          const size_t sub = (((size_t)(oz >> 1) * HD) + (oy >> 1)) * HD + (ox >> 1);
          const size_t addr = (((size_t)ob * 8 + pp) * (HD * HD * HD) + sub) * COUT + n;
          float vv = fmaxf(acc[f][nq][r] + bv, 0.f);
          unsigned short h, l;
          split_bf(vv, h, l);
          outh[addr] = h;
          outl[addr] = l;
        }
      }
    }
  } else {
#pragma unroll
    for (int f = 0; f < MREP; ++f) {
#pragma unroll
      for (int nq = 0; nq < 4; ++nq) {
        const int n = nBase + nq * 16 + mlane;
#pragma unroll
        for (int r = 0; r < 4; ++r) {
          const int mrow = mWave + f * 16 + kgrp * 4 + r;
          partial[((size_t)skid * M + mrow) * COUT + n] = acc[f][nq][r];
        }
      }
    }
  }
}

// ---------------------------------------------------------------------------
// Reduce split-K fp32 partials + bias + ReLU.
// F32OUT: linear [M][COUT] fp32 (for final 1x1).
// else: parity-split bf16 hi/lo for next stage (producer dims DOP).
// ---------------------------------------------------------------------------
template <int COUT, int SK, int M, int DOP, bool F32OUT>
__global__ __launch_bounds__(256) void reduce_split(
    const float* __restrict__ partial, const float* __restrict__ bias,
    unsigned short* __restrict__ oh, unsigned short* __restrict__ ol,
    float* __restrict__ of) {
  constexpr int LD = ilog2(DOP);
  constexpr int HD = DOP / 2;
  int idx = blockIdx.x * 256 + threadIdx.x;  // mrow*COUT + n
  int n = idx & (COUT - 1);
  int mrow = idx / COUT;
  float s = 0.f;
#pragma unroll
  for (int k = 0; k < SK; ++k) s += partial[(size_t)k * M * COUT + idx];
  float v = fmaxf(s + bias[n], 0.f);
  if constexpr (F32OUT) {
    of[idx] = v;
  } else {
    const int ox = mrow & (DOP - 1);
    const int oy = (mrow >> LD) & (DOP - 1);
    const int oz = (mrow >> (2 * LD)) & (DOP - 1);
    const int ob = mrow >> (3 * LD);
    const int pp = (oz & 1) * 4 + (oy & 1) * 2 + (ox & 1);
    const size_t sub = (((size_t)(oz >> 1) * HD) + (oy >> 1)) * HD + (ox >> 1);
    const size_t addr = (((size_t)ob * 8 + pp) * (HD * HD * HD) + sub) * COUT + n;
    unsigned short h, l;
    split_bf(v, h, l);
    oh[addr] = h;
    ol[addr] = l;
  }
}

// ---------------------------------------------------------------------------
// Final 1x1x1 conv: h5 [128][512] fp32 x woutT [512][256] -> out NCDHW
// ---------------------------------------------------------------------------
__global__ __launch_bounds__(256) void conv1x1_final(
    const float* __restrict__ h5, const float* __restrict__ wt,
    float* __restrict__ out) {
  int p = blockIdx.x;    // 0..127 = b*64 + s
  int co = threadIdx.x;  // 0..255
  int b = p >> 6;
  int s = p & 63;
  const float* hp = h5 + (size_t)p * 512;
  float acc = 0.f;
#pragma unroll 8
  for (int c = 0; c < 512; ++c) acc = fmaf(hp[c], wt[(size_t)c * 256 + co], acc);
  out[((size_t)b * 256 + co) * 64 + s] = acc;
}

// ---------------------------------------------------------------------------
extern "C" void kernel_launch(void* const* d_in, const int* in_sizes, int n_in,
                              void* d_out, int out_size, void* d_ws,
                              size_t ws_size, hipStream_t stream) {
  const float* x = (const float*)d_in[0];
  const float* w1 = (const float*)d_in[1];
  const float* g1 = (const float*)d_in[2];
  const float* bb1 = (const float*)d_in[3];
  const float* m1 = (const float*)d_in[4];
  const float* v1 = (const float*)d_in[5];
  const float* w2 = (const float*)d_in[6];
  const float* g2 = (const float*)d_in[7];
  const float* bb2 = (const float*)d_in[8];
  const float* m2 = (const float*)d_in[9];
  const float* v2 = (const float*)d_in[10];
  const float* w3 = (const float*)d_in[11];
  const float* g3 = (const float*)d_in[12];
  const float* bb3 = (const float*)d_in[13];
  const float* m3 = (const float*)d_in[14];
  const float* v3 = (const float*)d_in[15];
  const float* w4 = (const float*)d_in[16];
  const float* g4 = (const float*)d_in[17];
  const float* bb4 = (const float*)d_in[18];
  const float* m4 = (const float*)d_in[19];
  const float* v4 = (const float*)d_in[20];
  const float* w5 = (const float*)d_in[21];
  const float* g5 = (const float*)d_in[22];
  const float* bb5 = (const float*)d_in[23];
  const float* m5 = (const float*)d_in[24];
  const float* v5 = (const float*)d_in[25];
  const float* w_out = (const float*)d_in[26];
  (void)in_sizes; (void)n_in; (void)out_size; (void)ws_size;

  char* base = (char*)d_ws;
  size_t off = 0;
  auto take = [&](size_t bytes) {
    char* p = base + off;
    off = (off + bytes + 255) & ~(size_t)255;
    return p;
  };
  float* wt1 = (float*)take(3456 * 4);
  unsigned short* w2h = (unsigned short*)take(55296 * 2);
  unsigned short* w2l = (unsigned short*)take(55296 * 2);
  unsigned short* w3h = (unsigned short*)take(221184 * 2);
  unsigned short* w3l = (unsigned short*)take(221184 * 2);
  unsigned short* w4h = (unsigned short*)take(884736 * 2);
  unsigned short* w4l = (unsigned short*)take(884736 * 2);
  unsigned short* w5h = (unsigned short*)take(3538944 * 2);
  unsigned short* w5l = (unsigned short*)take(3538944 * 2);
  float* woutT = (float*)take(131072 * 4);
  float* bs1 = (float*)take(32 * 4);
  float* bs2 = (float*)take(64 * 4);
  float* bs3 = (float*)take(128 * 4);
  float* bs4 = (float*)take(256 * 4);
  float* bs5 = (float*)take(512 * 4);
  unsigned short* h1h = (unsigned short*)take((size_t)16777216 * 2);
  unsigned short* h1l = (unsigned short*)take((size_t)16777216 * 2);
  unsigned short* h2h = (unsigned short*)take((size_t)4194304 * 2);
  unsigned short* h2l = (unsigned short*)take((size_t)4194304 * 2);

  char* AR = (char*)h1h;  // h1 dead after stage 2
  float* p3 = (float*)AR;                        // 3*8192*128*4  = 12.58 MB
  float* p4 = (float*)AR;                        // 9*1024*256*4  =  9.44 MB
  float* p5 = (float*)AR;                        // 27*128*512*4  =  7.08 MB
  char* AR2 = AR + ((size_t)16 << 20);
  unsigned short* h3h = (unsigned short*)AR2;
  unsigned short* h3l = (unsigned short*)(AR2 + 2097152);
  unsigned short* h4h = (unsigned short*)(AR2 + 2 * 2097152);
  unsigned short* h4l = (unsigned short*)(AR2 + 2 * 2097152 + 524288);
  float* h5 = (float*)(AR2 + 2 * 2097152 + 2 * 524288);

  // --- weight repacks ---
  repack_kernel<4, 32><<<(3456 + 255) / 256, 256, 0, stream>>>(
      w1, g1, bb1, m1, v1, wt1, bs1);
  repack_bf16<32, 64><<<(55296 + 255) / 256, 256, 0, stream>>>(
      w2, g2, bb2, m2, v2, w2h, w2l, bs2);
  repack_bf16<64, 128><<<(221184 + 255) / 256, 256, 0, stream>>>(
      w3, g3, bb3, m3, v3, w3h, w3l, bs3);
  repack_bf16<128, 256><<<(884736 + 255) / 256, 256, 0, stream>>>(
      w4, g4, bb4, m4, v4, w4h, w4l, bs4);
  repack_bf16<256, 512><<<(3538944 + 255) / 256, 256, 0, stream>>>(
      w5, g5, bb5, m5, v5, w5h, w5l, bs5);
  repack_wout<<<512, 256, 0, stream>>>(w_out, woutT);

  // --- stage 1: fp32 direct, [2,4,128^3] -> parity-split [2][8][32^3][32] ---
  conv1_direct<<<2048, 256, 0, stream>>>(x, wt1, bs1, h1h, h1l);

  // --- stage 2: MFMA M=65536 N=64, MREP=2, SK=1 fused ---
  conv_mfma<32, 64, 32, 1, 2><<<dim3(512, 1, 1), 256, 0, stream>>>(
      h1h, h1l, w2h, w2l, bs2, h2h, h2l, nullptr);

  // --- stage 3: MFMA M=8192 N=128, MREP=2, SK=3 ---
  conv_mfma<64, 128, 16, 3, 2><<<dim3(64, 2, 3), 256, 0, stream>>>(
      h2h, h2l, w3h, w3l, bs3, nullptr, nullptr, p3);
  reduce_split<128, 3, 8192, 16, false><<<4096, 256, 0, stream>>>(
      p3, bs3, h3h, h3l, nullptr);

  // --- stage 4: MFMA M=1024 N=256, MREP=1, SK=9 ---
  conv_mfma<128, 256, 8, 9, 1><<<dim3(16, 4, 9), 256, 0, stream>>>(
      h3h, h3l, w4h, w4l, bs4, nullptr, nullptr, p4);
  reduce_split<256, 9, 1024, 8, false><<<1024, 256, 0, stream>>>(
      p4, bs4, h4h, h4l, nullptr);

  // --- stage 5: MFMA M=128 N=512, MREP=1, SK=27, fp32 out ---
  conv_mfma<256, 512, 4, 27, 1><<<dim3(2, 8, 27), 256, 0, stream>>>(
      h4h, h4l, w5h, w5l, bs5, nullptr, nullptr, p5);
  reduce_split<512, 27, 128, 4, true><<<256, 256, 0, stream>>>(
      p5, bs5, nullptr, nullptr, h5);

  // --- final 1x1x1 conv ---
  conv1x1_final<<<128, 256, 0, stream>>>(h5, woutT, (float*)d_out);
}